// Round 4
// baseline (162.011 us; speedup 1.0000x reference)
//
#include <hip/hip_runtime.h>
#include <hip/hip_bf16.h>
#include <float.h>

#define N_PATCH 216
#define DIM 125
#define HEADS 8
#define HEAD_DIM 64
#define QK 512           // HEADS*HEAD_DIM
#define NH (HEADS*N_PATCH)   // 1728

// ws layout (floats):
//  Wt  : [125][1024]  off 0        (128000)  cols 0-511 = Wq rows, 512-1023 = Wk rows
//  q   : [216][512]   off 128000   (110592)
//  k   : [216][512]   off 238592   (110592)
//  stats: [16][2]     off 349184   (32)   raw sums {S, SS}; idx = (isK*8+h)
//  Qt  : [8][64][216] off 349216   (110592)
//  Kn  : [8][216][64] off 459808   (110592)
//  x4  : [72][72][72] off 570400   (373248)
//  t1  : [20][72][72] off 943648   (103680)

// Transpose Wq/Wk [1024 rows][125] -> Wt [125][1024]; block 0 also zeroes stats.
__global__ __launch_bounds__(256) void k_wt(const float* __restrict__ Wq,
        const float* __restrict__ Wk, float* __restrict__ Wt, float* __restrict__ stats) {
    __shared__ float lds[64*DIM];            // 32 KB
    const int bid = blockIdx.x;              // 0..15, 64 W-rows each
    const int t = threadIdx.x;
    if (bid == 0 && t < 32) stats[t] = 0.f;  // zero the atomic accumulators
    const float* src = (bid < 8) ? Wq : Wk;
    const int rbase = (bid & 7)*64*DIM;
    for (int idx = t; idx < 64*DIM; idx += 256)
        lds[idx] = src[rbase + idx];         // fully contiguous
    __syncthreads();
    const int lane = t & 63, ii = t >> 6;
    const int c0 = bid*64;
    for (int i = ii; i < DIM; i += 4)
        Wt[i*1024 + c0 + lane] = lds[lane*DIM + i];
}

// QK projection + fused BN-stats accumulation (atomics into stats[]).
__global__ __launch_bounds__(512) void k_qk(const float* __restrict__ x,
        const float* __restrict__ Wt, float* __restrict__ q, float* __restrict__ k,
        float* __restrict__ stats) {
    __shared__ float xs[DIM];
    const int n = blockIdx.x, t = threadIdx.x;
    if (t < DIM) xs[t] = x[n*DIM + t];
    __syncthreads();
    const float2* Wt2 = (const float2*)Wt;
    float2 acc = {0.f, 0.f};
    #pragma unroll 5
    for (int i = 0; i < DIM; ++i) {
        float2 w = Wt2[i*512 + t];           // lanes consecutive -> coalesced
        float xv = xs[i];
        acc.x = fmaf(xv, w.x, acc.x);
        acc.y = fmaf(xv, w.y, acc.y);
    }
    int c = 2*t;
    if (c < QK) *(float2*)(q + n*QK + c) = acc;
    else        *(float2*)(k + n*QK + (c - QK)) = acc;
    // stats: 32 consecutive threads = one head's 64 outputs
    float s  = acc.x + acc.y;
    float ss = acc.x*acc.x + acc.y*acc.y;
    #pragma unroll
    for (int off = 16; off; off >>= 1) {
        s  += __shfl_down(s,  off, 32);
        ss += __shfl_down(ss, off, 32);
    }
    if ((t & 31) == 0) {
        int isK = (c >= QK) ? 1 : 0;
        int h = (c & (QK-1)) >> 6;
        atomicAdd(&stats[(isK*8+h)*2],   s);
        atomicAdd(&stats[(isK*8+h)*2+1], ss);
    }
}

__global__ __launch_bounds__(256) void k_norm(const float* __restrict__ q,
        const float* __restrict__ k, const float* __restrict__ stats,
        const float* __restrict__ bnw, const float* __restrict__ bnb,
        float* __restrict__ Qt, float* __restrict__ Kn) {
    int gw = blockIdx.x*4 + (threadIdx.x >> 6);   // 0..3455
    int lane = threadIdx.x & 63;
    int isK = (gw >= NH) ? 1 : 0;
    int r = isK ? gw - NH : gw;
    int h = r / N_PATCH, n = r % N_PATCH;
    const float* src = isK ? k : q;
    int sb = (isK*8 + h)*2;
    const float invN = 1.0f/13824.0f;
    float mean = stats[sb]*invN;
    float var  = stats[sb+1]*invN - mean*mean;
    float inv = 1.0f / sqrtf(var + 1e-5f);
    float w = bnw[h], b = bnb[h];
    float v = src[n*QK + h*HEAD_DIM + lane];
    float xh = (v - mean)*inv*w + b;
    float sq = xh*xh;
    #pragma unroll
    for (int off = 32; off; off >>= 1) sq += __shfl_xor(sq, off, 64);
    float nrm = fmaxf(sqrtf(sq), 1e-12f);
    float o = xh / nrm;
    if (isK) Kn[(h*N_PATCH + n)*HEAD_DIM + lane] = o;
    else     Qt[h*HEAD_DIM*N_PATCH + lane*N_PATCH + n] = o;
}

// Sort-free sparsemax: one WAVE per column c = h*216+m; 4 z's per lane in regs.
// tau = root of g(tau) = sum(max(z-tau,0)) - 1 (convex piecewise-linear) via Newton.
__global__ __launch_bounds__(256) void k_sparse(const float* __restrict__ Qt,
        const float* __restrict__ Kn, float* __restrict__ att, float* __restrict__ x4) {
    const int wv = threadIdx.x >> 6, lane = threadIdx.x & 63;
    const int c = blockIdx.x*4 + wv;         // 0..1727
    const int h = c / N_PATCH, m = c % N_PATCH;
    __shared__ float ks[4][HEAD_DIM];
    ks[wv][lane] = Kn[(h*N_PATCH+m)*HEAD_DIM + lane];
    __syncthreads();
    const float* qh = Qt + h*HEAD_DIM*N_PATCH;
    float z0=0.f, z1=0.f, z2=0.f, z3=0.f;
    const bool v3 = (lane < N_PATCH - 192);  // lane<24
    #pragma unroll 8
    for (int d = 0; d < HEAD_DIM; ++d) {
        float kd = ks[wv][d];                // LDS broadcast
        z0 = fmaf(qh[d*N_PATCH + lane],       kd, z0);
        z1 = fmaf(qh[d*N_PATCH + 64 + lane],  kd, z1);
        z2 = fmaf(qh[d*N_PATCH + 128 + lane], kd, z2);
        if (v3) z3 = fmaf(qh[d*N_PATCH + 192 + lane], kd, z3);
    }
    const float scale = 0.08944271909999159f;  // 1/sqrt(125)
    z0 *= scale; z1 *= scale; z2 *= scale; z3 *= scale;
    // wave max
    float mx = fmaxf(fmaxf(z0, z1), fmaxf(z2, v3 ? z3 : -FLT_MAX));
    #pragma unroll
    for (int off = 32; off; off >>= 1) mx = fmaxf(mx, __shfl_xor(mx, off, 64));
    float tau = mx - 1.0f;                   // g(tau0) >= 0
    for (int it = 0; it < 48; ++it) {
        float g = fmaxf(z0-tau,0.f) + fmaxf(z1-tau,0.f) + fmaxf(z2-tau,0.f)
                + (v3 ? fmaxf(z3-tau,0.f) : 0.f);
        float cnt = (z0>tau ? 1.f:0.f) + (z1>tau ? 1.f:0.f) + (z2>tau ? 1.f:0.f)
                  + ((v3 && z3>tau) ? 1.f:0.f);
        #pragma unroll
        for (int off = 32; off; off >>= 1) {
            g   += __shfl_xor(g,   off, 64);
            cnt += __shfl_xor(cnt, off, 64);
        }
        g -= 1.0f;
        if (g <= 1e-7f) break;               // wave-uniform
        tau += g / cnt;                      // Newton step (monotone from left)
    }
    // emit
    #pragma unroll
    for (int j = 0; j < 4; ++j) {
        int n = lane + 64*j;
        if (n >= N_PATCH) break;
        float zz = (j==0) ? z0 : (j==1) ? z1 : (j==2) ? z2 : z3;
        float a = fmaxf(zz - tau, 0.f);
        att[n*NH + c] = a;
        int nh2 = n / 27;
        int d0 = nh2 >> 2, d1 = (nh2 >> 1) & 1, d2 = nh2 & 1;
        int r = (n % 27)*NH + c;
        int d3 = r / 7776; r -= d3*7776;
        int d4 = r / 1296; r -= d4*1296;
        int d5 = r / 216;  r -= d5*216;
        int d6 = r / 36;   r -= d6*36;
        int d7 = r / 6;
        int d8 = r - d7*6;
        int ii  = d0*36 + d3*6 + d6;
        int jj  = d1*36 + d4*6 + d7;
        int kk2 = d2*36 + d5*6 + d8;
        x4[(ii*72 + jj)*72 + kk2] = a;
    }
}

__global__ __launch_bounds__(256) void k_tcl1(const float* __restrict__ W1,
        const float* __restrict__ x4, float* __restrict__ t1) {
    int o = blockIdx.x*256 + threadIdx.x;    // exactly 103680
    int a = o / 5184, jk = o % 5184;
    float acc = 0.f;
    #pragma unroll 8
    for (int i = 0; i < 72; ++i) acc += W1[a*72+i]*x4[i*5184 + jk];
    t1[o] = acc;
}

// Fused modes 2+3: one block per a; t1-slab and t2-slab live in LDS.
__global__ __launch_bounds__(512) void k_tcl23(const float* __restrict__ W2,
        const float* __restrict__ W3, const float* __restrict__ t1,
        float* __restrict__ out0) {
    __shared__ float t1a[5184];
    __shared__ float t2a[1440];
    const int a = blockIdx.x, t = threadIdx.x;
    for (int i = t; i < 5184; i += 512) t1a[i] = t1[a*5184 + i];
    __syncthreads();
    for (int idx = t; idx < 1440; idx += 512) {
        int cc = idx / 72, kk = idx % 72;
        float acc = 0.f;
        #pragma unroll 8
        for (int j = 0; j < 72; ++j) acc += W2[cc*72+j]*t1a[j*72 + kk];
        t2a[idx] = acc;
    }
    __syncthreads();
    if (t < 400) {
        int cc = t / 20, dd = t % 20;
        float acc = 0.f;
        #pragma unroll 8
        for (int kq = 0; kq < 72; ++kq) acc += W3[dd*72+kq]*t2a[cc*72 + kq];
        out0[(a*20 + cc)*20 + dd] = tanhf(acc);
    }
}

extern "C" void kernel_launch(void* const* d_in, const int* in_sizes, int n_in,
                              void* d_out, int out_size, void* d_ws, size_t ws_size,
                              hipStream_t stream) {
    const float* patches = (const float*)d_in[0];
    const float* Wq = (const float*)d_in[1];
    const float* Wk = (const float*)d_in[2];
    const float* bnw = (const float*)d_in[3];
    const float* bnb = (const float*)d_in[4];
    const float* W1 = (const float*)d_in[5];
    const float* W2 = (const float*)d_in[6];
    const float* W3 = (const float*)d_in[7];
    float* out = (float*)d_out;
    float* ws = (float*)d_ws;

    float* Wt    = ws;
    float* q     = ws + 128000;
    float* k     = ws + 238592;
    float* stats = ws + 349184;
    float* Qt    = ws + 349216;
    float* Kn    = ws + 459808;
    float* x4    = ws + 570400;
    float* t1    = ws + 943648;

    float* out0 = out;          // tanh(x5): 8000 floats
    float* att  = out + 8000;   // att: 216*1728 floats

    hipLaunchKernelGGL(k_wt,     dim3(16),   dim3(256), 0, stream, Wq, Wk, Wt, stats);
    hipLaunchKernelGGL(k_qk,     dim3(216),  dim3(512), 0, stream, patches, Wt, q, k, stats);
    hipLaunchKernelGGL(k_norm,   dim3(864),  dim3(256), 0, stream, q, k, stats, bnw, bnb, Qt, Kn);
    hipLaunchKernelGGL(k_sparse, dim3(432),  dim3(256), 0, stream, Qt, Kn, att, x4);
    hipLaunchKernelGGL(k_tcl1,   dim3(405),  dim3(256), 0, stream, W1, x4, t1);
    hipLaunchKernelGGL(k_tcl23,  dim3(20),   dim3(512), 0, stream, W2, W3, t1, out0);
}

// Round 5
// 139.705 us; speedup vs baseline: 1.1597x; 1.1597x over previous
//
#include <hip/hip_runtime.h>
#include <hip/hip_bf16.h>
#include <float.h>

#define N_PATCH 216
#define DIM 125
#define HEADS 8
#define HEAD_DIM 64
#define QK 512           // HEADS*HEAD_DIM
#define NH (HEADS*N_PATCH)   // 1728

// ws layout (floats):
//  Wt  : [125][1024]  off 0        (128000)  cols 0-511 = Wq rows, 512-1023 = Wk rows
//  q   : [216][512]   off 128000   (110592)
//  k   : [216][512]   off 238592   (110592)
//  stats: [16][2]     off 349184   (32)   raw sums {S, SS}; idx = (isK*8+h)
//  Qt  : [8][64][216] off 349216   (110592)
//  Kn  : [8][216][64] off 459808   (110592)
//  x4  : [72][72][72] off 570400   (373248)
//  t1  : [20][72][72] off 943648   (103680)

// Transpose Wq/Wk [1024 rows][125] -> Wt [125][1024]; block 0 also zeroes stats.
__global__ __launch_bounds__(256) void k_wt(const float* __restrict__ Wq,
        const float* __restrict__ Wk, float* __restrict__ Wt, float* __restrict__ stats) {
    __shared__ float lds[64*DIM];            // 32 KB
    const int bid = blockIdx.x;              // 0..15, 64 W-rows each
    const int t = threadIdx.x;
    if (bid == 0 && t < 32) stats[t] = 0.f;  // zero the atomic accumulators
    const float* src = (bid < 8) ? Wq : Wk;
    const int rbase = (bid & 7)*64*DIM;
    for (int idx = t; idx < 64*DIM; idx += 256)
        lds[idx] = src[rbase + idx];         // fully contiguous
    __syncthreads();
    const int lane = t & 63, ii = t >> 6;
    const int c0 = bid*64;
    for (int i = ii; i < DIM; i += 4)
        Wt[i*1024 + c0 + lane] = lds[lane*DIM + i];
}

// QK projection + fused BN-stats. 256 threads; thread t owns float4 cols 4t..4t+3.
// 5-deep rotating register pipeline => ~5 global loads in flight (was 1 @ VGPR=12).
__global__ __launch_bounds__(256) void k_qk(const float* __restrict__ x,
        const float* __restrict__ Wt, float* __restrict__ q, float* __restrict__ k,
        float* __restrict__ stats) {
    __shared__ float xs[DIM];
    const int n = blockIdx.x, t = threadIdx.x;
    if (t < DIM) xs[t] = x[n*DIM + t];
    __syncthreads();
    const float4* Wt4 = (const float4*)Wt;   // [125][256] of float4
    float4 w0 = Wt4[0*256 + t];
    float4 w1 = Wt4[1*256 + t];
    float4 w2 = Wt4[2*256 + t];
    float4 w3 = Wt4[3*256 + t];
    float4 w4 = Wt4[4*256 + t];
    float4 acc = {0.f, 0.f, 0.f, 0.f};
    #pragma unroll 1
    for (int g = 0; g < 120; g += 5) {
        float xv;
        xv = xs[g+0];
        acc.x = fmaf(xv, w0.x, acc.x); acc.y = fmaf(xv, w0.y, acc.y);
        acc.z = fmaf(xv, w0.z, acc.z); acc.w = fmaf(xv, w0.w, acc.w);
        w0 = Wt4[(g+5)*256 + t];
        xv = xs[g+1];
        acc.x = fmaf(xv, w1.x, acc.x); acc.y = fmaf(xv, w1.y, acc.y);
        acc.z = fmaf(xv, w1.z, acc.z); acc.w = fmaf(xv, w1.w, acc.w);
        w1 = Wt4[(g+6)*256 + t];
        xv = xs[g+2];
        acc.x = fmaf(xv, w2.x, acc.x); acc.y = fmaf(xv, w2.y, acc.y);
        acc.z = fmaf(xv, w2.z, acc.z); acc.w = fmaf(xv, w2.w, acc.w);
        w2 = Wt4[(g+7)*256 + t];
        xv = xs[g+3];
        acc.x = fmaf(xv, w3.x, acc.x); acc.y = fmaf(xv, w3.y, acc.y);
        acc.z = fmaf(xv, w3.z, acc.z); acc.w = fmaf(xv, w3.w, acc.w);
        w3 = Wt4[(g+8)*256 + t];
        xv = xs[g+4];
        acc.x = fmaf(xv, w4.x, acc.x); acc.y = fmaf(xv, w4.y, acc.y);
        acc.z = fmaf(xv, w4.z, acc.z); acc.w = fmaf(xv, w4.w, acc.w);
        w4 = Wt4[(g+9)*256 + t];
    }
    {   // epilogue: rows 120..124
        float xv;
        xv = xs[120];
        acc.x = fmaf(xv, w0.x, acc.x); acc.y = fmaf(xv, w0.y, acc.y);
        acc.z = fmaf(xv, w0.z, acc.z); acc.w = fmaf(xv, w0.w, acc.w);
        xv = xs[121];
        acc.x = fmaf(xv, w1.x, acc.x); acc.y = fmaf(xv, w1.y, acc.y);
        acc.z = fmaf(xv, w1.z, acc.z); acc.w = fmaf(xv, w1.w, acc.w);
        xv = xs[122];
        acc.x = fmaf(xv, w2.x, acc.x); acc.y = fmaf(xv, w2.y, acc.y);
        acc.z = fmaf(xv, w2.z, acc.z); acc.w = fmaf(xv, w2.w, acc.w);
        xv = xs[123];
        acc.x = fmaf(xv, w3.x, acc.x); acc.y = fmaf(xv, w3.y, acc.y);
        acc.z = fmaf(xv, w3.z, acc.z); acc.w = fmaf(xv, w3.w, acc.w);
        xv = xs[124];
        acc.x = fmaf(xv, w4.x, acc.x); acc.y = fmaf(xv, w4.y, acc.y);
        acc.z = fmaf(xv, w4.z, acc.z); acc.w = fmaf(xv, w4.w, acc.w);
    }
    const int c = 4*t;
    if (c < QK) *(float4*)(q + n*QK + c) = acc;
    else        *(float4*)(k + n*QK + (c - QK)) = acc;
    // stats: 16 consecutive threads = one head's 64 outputs
    float s  = acc.x + acc.y + acc.z + acc.w;
    float ss = acc.x*acc.x + acc.y*acc.y + acc.z*acc.z + acc.w*acc.w;
    #pragma unroll
    for (int off = 8; off; off >>= 1) {
        s  += __shfl_down(s,  off, 16);
        ss += __shfl_down(ss, off, 16);
    }
    if ((t & 15) == 0) {
        int isK = (c >= QK) ? 1 : 0;
        int h = (c & (QK-1)) >> 6;
        atomicAdd(&stats[(isK*8+h)*2],   s);
        atomicAdd(&stats[(isK*8+h)*2+1], ss);
    }
}

__global__ __launch_bounds__(256) void k_norm(const float* __restrict__ q,
        const float* __restrict__ k, const float* __restrict__ stats,
        const float* __restrict__ bnw, const float* __restrict__ bnb,
        float* __restrict__ Qt, float* __restrict__ Kn) {
    int gw = blockIdx.x*4 + (threadIdx.x >> 6);   // 0..3455
    int lane = threadIdx.x & 63;
    int isK = (gw >= NH) ? 1 : 0;
    int r = isK ? gw - NH : gw;
    int h = r / N_PATCH, n = r % N_PATCH;
    const float* src = isK ? k : q;
    int sb = (isK*8 + h)*2;
    const float invN = 1.0f/13824.0f;
    float mean = stats[sb]*invN;
    float var  = stats[sb+1]*invN - mean*mean;
    float inv = 1.0f / sqrtf(var + 1e-5f);
    float w = bnw[h], b = bnb[h];
    float v = src[n*QK + h*HEAD_DIM + lane];
    float xh = (v - mean)*inv*w + b;
    float sq = xh*xh;
    #pragma unroll
    for (int off = 32; off; off >>= 1) sq += __shfl_xor(sq, off, 64);
    float nrm = fmaxf(sqrtf(sq), 1e-12f);
    float o = xh / nrm;
    if (isK) Kn[(h*N_PATCH + n)*HEAD_DIM + lane] = o;
    else     Qt[h*HEAD_DIM*N_PATCH + lane*N_PATCH + n] = o;
}

// Sort-free sparsemax: one WAVE per column c = h*216+m; 4 z's per lane in regs.
// tau = root of g(tau) = sum(max(z-tau,0)) - 1 (convex piecewise-linear) via Newton.
__global__ __launch_bounds__(256) void k_sparse(const float* __restrict__ Qt,
        const float* __restrict__ Kn, float* __restrict__ att, float* __restrict__ x4) {
    const int wv = threadIdx.x >> 6, lane = threadIdx.x & 63;
    const int c = blockIdx.x*4 + wv;         // 0..1727
    const int h = c / N_PATCH, m = c % N_PATCH;
    __shared__ float ks[4][HEAD_DIM];
    ks[wv][lane] = Kn[(h*N_PATCH+m)*HEAD_DIM + lane];
    __syncthreads();
    const float* qh = Qt + h*HEAD_DIM*N_PATCH;
    float z0=0.f, z1=0.f, z2=0.f, z3=0.f;
    const bool v3 = (lane < N_PATCH - 192);  // lane<24
    #pragma unroll 8
    for (int d = 0; d < HEAD_DIM; ++d) {
        float kd = ks[wv][d];                // LDS broadcast
        z0 = fmaf(qh[d*N_PATCH + lane],       kd, z0);
        z1 = fmaf(qh[d*N_PATCH + 64 + lane],  kd, z1);
        z2 = fmaf(qh[d*N_PATCH + 128 + lane], kd, z2);
        if (v3) z3 = fmaf(qh[d*N_PATCH + 192 + lane], kd, z3);
    }
    const float scale = 0.08944271909999159f;  // 1/sqrt(125)
    z0 *= scale; z1 *= scale; z2 *= scale; z3 *= scale;
    // wave max
    float mx = fmaxf(fmaxf(z0, z1), fmaxf(z2, v3 ? z3 : -FLT_MAX));
    #pragma unroll
    for (int off = 32; off; off >>= 1) mx = fmaxf(mx, __shfl_xor(mx, off, 64));
    float tau = mx - 1.0f;                   // g(tau0) >= 0
    for (int it = 0; it < 20; ++it) {
        float g = fmaxf(z0-tau,0.f) + fmaxf(z1-tau,0.f) + fmaxf(z2-tau,0.f)
                + (v3 ? fmaxf(z3-tau,0.f) : 0.f);
        float cnt = (z0>tau ? 1.f:0.f) + (z1>tau ? 1.f:0.f) + (z2>tau ? 1.f:0.f)
                  + ((v3 && z3>tau) ? 1.f:0.f);
        #pragma unroll
        for (int off = 32; off; off >>= 1) {
            g   += __shfl_xor(g,   off, 64);
            cnt += __shfl_xor(cnt, off, 64);
        }
        g -= 1.0f;
        if (g <= 1e-6f) break;               // wave-uniform
        tau += g / cnt;                      // Newton step (monotone from left)
    }
    // emit
    #pragma unroll
    for (int j = 0; j < 4; ++j) {
        int n = lane + 64*j;
        if (n >= N_PATCH) break;
        float zz = (j==0) ? z0 : (j==1) ? z1 : (j==2) ? z2 : z3;
        float a = fmaxf(zz - tau, 0.f);
        att[n*NH + c] = a;
        int nh2 = n / 27;
        int d0 = nh2 >> 2, d1 = (nh2 >> 1) & 1, d2 = nh2 & 1;
        int r = (n % 27)*NH + c;
        int d3 = r / 7776; r -= d3*7776;
        int d4 = r / 1296; r -= d4*1296;
        int d5 = r / 216;  r -= d5*216;
        int d6 = r / 36;   r -= d6*36;
        int d7 = r / 6;
        int d8 = r - d7*6;
        int ii  = d0*36 + d3*6 + d6;
        int jj  = d1*36 + d4*6 + d7;
        int kk2 = d2*36 + d5*6 + d8;
        x4[(ii*72 + jj)*72 + kk2] = a;
    }
}

__global__ __launch_bounds__(256) void k_tcl1(const float* __restrict__ W1,
        const float* __restrict__ x4, float* __restrict__ t1) {
    int o = blockIdx.x*256 + threadIdx.x;    // exactly 103680
    int a = o / 5184, jk = o % 5184;
    float acc = 0.f;
    #pragma unroll 8
    for (int i = 0; i < 72; ++i) acc += W1[a*72+i]*x4[i*5184 + jk];
    t1[o] = acc;
}

// Fused modes 2+3: one block per a; t1-slab and t2-slab live in LDS.
__global__ __launch_bounds__(512) void k_tcl23(const float* __restrict__ W2,
        const float* __restrict__ W3, const float* __restrict__ t1,
        float* __restrict__ out0) {
    __shared__ float t1a[5184];
    __shared__ float t2a[1440];
    const int a = blockIdx.x, t = threadIdx.x;
    for (int i = t; i < 5184; i += 512) t1a[i] = t1[a*5184 + i];
    __syncthreads();
    for (int idx = t; idx < 1440; idx += 512) {
        int cc = idx / 72, kk = idx % 72;
        float acc = 0.f;
        #pragma unroll 8
        for (int j = 0; j < 72; ++j) acc += W2[cc*72+j]*t1a[j*72 + kk];
        t2a[idx] = acc;
    }
    __syncthreads();
    if (t < 400) {
        int cc = t / 20, dd = t % 20;
        float acc = 0.f;
        #pragma unroll 8
        for (int kq = 0; kq < 72; ++kq) acc += W3[dd*72+kq]*t2a[cc*72 + kq];
        out0[(a*20 + cc)*20 + dd] = tanhf(acc);
    }
}

extern "C" void kernel_launch(void* const* d_in, const int* in_sizes, int n_in,
                              void* d_out, int out_size, void* d_ws, size_t ws_size,
                              hipStream_t stream) {
    const float* patches = (const float*)d_in[0];
    const float* Wq = (const float*)d_in[1];
    const float* Wk = (const float*)d_in[2];
    const float* bnw = (const float*)d_in[3];
    const float* bnb = (const float*)d_in[4];
    const float* W1 = (const float*)d_in[5];
    const float* W2 = (const float*)d_in[6];
    const float* W3 = (const float*)d_in[7];
    float* out = (float*)d_out;
    float* ws = (float*)d_ws;

    float* Wt    = ws;
    float* q     = ws + 128000;
    float* k     = ws + 238592;
    float* stats = ws + 349184;
    float* Qt    = ws + 349216;
    float* Kn    = ws + 459808;
    float* x4    = ws + 570400;
    float* t1    = ws + 943648;

    float* out0 = out;          // tanh(x5): 8000 floats
    float* att  = out + 8000;   // att: 216*1728 floats

    hipLaunchKernelGGL(k_wt,     dim3(16),   dim3(256), 0, stream, Wq, Wk, Wt, stats);
    hipLaunchKernelGGL(k_qk,     dim3(216),  dim3(256), 0, stream, patches, Wt, q, k, stats);
    hipLaunchKernelGGL(k_norm,   dim3(864),  dim3(256), 0, stream, q, k, stats, bnw, bnb, Qt, Kn);
    hipLaunchKernelGGL(k_sparse, dim3(432),  dim3(256), 0, stream, Qt, Kn, att, x4);
    hipLaunchKernelGGL(k_tcl1,   dim3(405),  dim3(256), 0, stream, W1, x4, t1);
    hipLaunchKernelGGL(k_tcl23,  dim3(20),   dim3(512), 0, stream, W2, W3, t1, out0);
}